// Round 2
// baseline (51796.167 us; speedup 1.0000x reference)
//
#include <hip/hip_runtime.h>
#include <hip/hip_bf16.h>
#include <stdint.h>

#define NS 4096     // samples / time steps
#define DT 1024     // dim_t == hidden == in
#define H4 4096     // 4*HID

// ---------- math helpers ----------
__device__ __forceinline__ float sigm_f(float x) { return 1.f / (1.f + __expf(-x)); }
__device__ __forceinline__ float tanh_f(float x) {
    float ax = fminf(fabsf(x), 15.f);                 // overflow-safe
    float t = 1.f - 2.f / (__expf(2.f * ax) + 1.f);
    return copysignf(t, x);
}

// ---------- sinusoidal embedding ----------
__global__ void emb_kernel(const int* __restrict__ ts, float* __restrict__ emb) {
    int t = blockIdx.x;
    int i = threadIdx.x;                 // 0..511
    float tv = (float)ts[t];
    const float c = -0.018024149455922082f;  // -ln(10000)/511
    float f = __expf(c * (float)i);
    float a = tv * f;
    float s, co;
    sincosf(a, &s, &co);
    emb[(size_t)t * DT + i] = s;
    emb[(size_t)t * DT + 512 + i] = co;
}

// ---------- generic C = A(M,K) @ B(Nc,K)^T + bias [+bias2] [+skip] [silu] ----------
// BM=128, BN=64, BK=16, 256 threads, each thread 8x4 outputs.
// XGMODE: 0 = plain fp32 C; 1 = bf16 XG layout; 2 = fp32 XG layout.
// XG layout: [step][l][k(=jj>>2)][q*4+r]; B/bias offset by blockIdx.z (=layer).
template <bool SILU, bool SKIP, int XGMODE>
__global__ __launch_bounds__(256) void gemm_bt(
    const float* __restrict__ A, const float* __restrict__ B,
    const float* __restrict__ bias, const float* __restrict__ bias2,
    const float* __restrict__ skip, float* __restrict__ Cf,
    __hip_bfloat16* __restrict__ Cb, int M, int Nc, int K)
{
    __shared__ __align__(16) float As[16][132];
    __shared__ __align__(16) float Bs[16][68];
    const int bn = blockIdx.x, bm = blockIdx.y, lz = blockIdx.z;
    if (XGMODE) {
        B     += (size_t)lz * H4 * DT;
        bias  += (size_t)lz * H4;
        bias2 += (size_t)lz * H4;
    }
    const int tid = threadIdx.x;
    const int tr = tid >> 4, tc = tid & 15;
    const int alr = tid >> 1, alc = (tid & 1) << 3;   // A: 128 rows x 16 cols, 8 floats/thread
    const int blr = tid >> 2, blc = (tid & 3) << 2;   // B: 64 rows x 16 cols, 4 floats/thread
    const float* Ap = A + (size_t)(bm * 128 + alr) * K + alc;
    const float* Bp = B + (size_t)(bn * 64 + blr) * K + blc;

    float acc[8][4];
#pragma unroll
    for (int i = 0; i < 8; i++)
#pragma unroll
        for (int j = 0; j < 4; j++) acc[i][j] = 0.f;

    for (int kk = 0; kk < K; kk += 16) {
        float4 a0 = *(const float4*)(Ap + kk);
        float4 a1 = *(const float4*)(Ap + kk + 4);
        float4 b0 = *(const float4*)(Bp + kk);
        __syncthreads();
        As[alc + 0][alr] = a0.x; As[alc + 1][alr] = a0.y;
        As[alc + 2][alr] = a0.z; As[alc + 3][alr] = a0.w;
        As[alc + 4][alr] = a1.x; As[alc + 5][alr] = a1.y;
        As[alc + 6][alr] = a1.z; As[alc + 7][alr] = a1.w;
        Bs[blc + 0][blr] = b0.x; Bs[blc + 1][blr] = b0.y;
        Bs[blc + 2][blr] = b0.z; Bs[blc + 3][blr] = b0.w;
        __syncthreads();
#pragma unroll
        for (int k = 0; k < 16; k++) {
            const float4 av0 = *(const float4*)&As[k][tr * 8];
            const float4 av1 = *(const float4*)&As[k][tr * 8 + 4];
            const float4 bv  = *(const float4*)&Bs[k][tc * 4];
            float aa[8] = {av0.x, av0.y, av0.z, av0.w, av1.x, av1.y, av1.z, av1.w};
            float bb[4] = {bv.x, bv.y, bv.z, bv.w};
#pragma unroll
            for (int i = 0; i < 8; i++)
#pragma unroll
                for (int j = 0; j < 4; j++)
                    acc[i][j] = fmaf(aa[i], bb[j], acc[i][j]);
        }
    }

#pragma unroll
    for (int i = 0; i < 8; i++) {
        int row = bm * 128 + tr * 8 + i;
#pragma unroll
        for (int j = 0; j < 4; j++) {
            int col = bn * 64 + tc * 4 + j;
            float v = acc[i][j] + bias[col];
            if (XGMODE) v += bias2[col];
            if (SKIP)   v += skip[(size_t)row * Nc + col];
            if (SILU)   v = v * (1.f / (1.f + __expf(-v)));
            if (XGMODE) {
                int q = col >> 10, jj = col & 1023;
                size_t idx = (size_t)row * 16384 + (size_t)lz * 4096
                           + ((size_t)(jj >> 2) << 4) + (q << 2) + (jj & 3);
                if (XGMODE == 2) Cf[idx] = v;
                else             Cb[idx] = __float2bfloat16(v);
            } else {
                Cf[(size_t)row * Nc + col] = v;
            }
        }
    }
}

// ---------- persistent sequential LSTM chain ----------
// 256 WGs x 256 threads (plain launch: 256 blocks always co-resident on 256 CUs).
// WG k owns h/c rows [4k,4k+4). Thread t: dot d=t>>4 (q=d>>2,r=d&3), sub-slice
// s=t&15 (h cols [64s,64s+64)). Whh held in registers: float w[4][64].
// h broadcast: double-buffered 1024-u64 arrays, word = (fp32 h)<<32 | epoch.
// Deadlock-free: slot for epoch e is only overwritten at e+2, which requires all
// WGs consumed e (each publisher of e+1 consumed all of e; every WG publishes).
template <typename XT>
__global__ __launch_bounds__(256, 1) void seq_kernel(
    const float* __restrict__ Whh,            // [4][4096][1024]
    const XT* __restrict__ XG,                // [step][l][k][16]
    float* __restrict__ hall,                 // [4096][1024]
    uint64_t* hbuf)                           // [2][1024]
{
    const int k = blockIdx.x;
    const int t = threadIdx.x;
    const int d = t >> 4, s = t & 15;
    const int q = d >> 2, r = d & 3;
    const int grow = q * 1024 + 4 * k + r;

    // rotated weight load: w[l][c4*4+j] = Whh[l][grow][s*64 + ((c4+s)&15)*4 + j]
    float w[4][64];
#pragma unroll
    for (int l = 0; l < 4; l++) {
        const float* src = Whh + ((size_t)l * H4 + grow) * 1024 + (s << 6);
#pragma unroll
        for (int c4 = 0; c4 < 16; c4++) {
            int ch = (c4 + s) & 15;
            float4 v = *(const float4*)(src + (ch << 2));
            w[l][c4 * 4 + 0] = v.x; w[l][c4 * 4 + 1] = v.y;
            w[l][c4 * 4 + 2] = v.z; w[l][c4 * 4 + 3] = v.w;
        }
    }

    __shared__ __align__(16) float lds_h[1024];
    __shared__ float lds_g[16];
    float creg = 0.f;   // c state for row 4k+t (threads t<4 only)

    for (int step = 0; step < NS; ++step) {
#pragma unroll
        for (int l = 0; l < 4; l++) {
            const int it = step * 4 + l + 1;             // epoch being produced
            const uint32_t rtag = (uint32_t)(it - 1);
            uint64_t* rb = (l & 1) ? (hbuf + 1024) : hbuf;        // (it-1)&1 == l&1
            uint64_t* wb = ((l + 1) & 1) ? (hbuf + 1024) : hbuf;  // it&1

            // poll + stage h into LDS (thread t owns words t, 256+t, 512+t, 768+t)
            uint32_t got = 0;
            int spins = 0;
            while (got != 0xFu) {
#pragma unroll
                for (int m = 0; m < 4; m++) {
                    if (!(got & (1u << m))) {
                        uint64_t u = __hip_atomic_load(&rb[(m << 8) + t],
                                                       __ATOMIC_RELAXED, __HIP_MEMORY_SCOPE_AGENT);
                        if ((uint32_t)u == rtag) {
                            lds_h[(m << 8) + t] = __uint_as_float((uint32_t)(u >> 32));
                            got |= (1u << m);
                        }
                    }
                }
                if (got != 0xFu && ++spins > 8) __builtin_amdgcn_s_sleep(1);
            }
            __syncthreads();   // B1: lds_h complete

            // partial dot over this thread's 64-col slice (rotated: 2-way conflicts only)
            float acc = 0.f;
            const float* hbase = &lds_h[s << 6];
#pragma unroll
            for (int c4 = 0; c4 < 16; c4++) {
                int ch = (c4 + s) & 15;
                const float4 hv = *(const float4*)(hbase + (ch << 2));
                acc = fmaf(w[l][c4 * 4 + 0], hv.x, acc);
                acc = fmaf(w[l][c4 * 4 + 1], hv.y, acc);
                acc = fmaf(w[l][c4 * 4 + 2], hv.z, acc);
                acc = fmaf(w[l][c4 * 4 + 3], hv.w, acc);
            }
            // reduce the 16 sub-slices (lanes xor 1,2,4,8 stay within the 16-lane group)
            acc += __shfl_xor(acc, 1);
            acc += __shfl_xor(acc, 2);
            acc += __shfl_xor(acc, 4);
            acc += __shfl_xor(acc, 8);
            if (s == 0) {
                float xg = (float)XG[(size_t)(step * 4 + l) * H4 + (k << 4) + d];
                lds_g[d] = acc + xg;
            }
            __syncthreads();   // B2: lds_g complete

            if (t < 4) {
                float gi = lds_g[t], gf = lds_g[4 + t], gg = lds_g[8 + t], go = lds_g[12 + t];
                float cn = sigm_f(gf) * creg + sigm_f(gi) * tanh_f(gg);
                creg = cn;
                float hn = sigm_f(go) * tanh_f(cn);
                if (l == 3) hall[(size_t)step * 1024 + (k << 2) + t] = hn;
                uint64_t word = ((uint64_t)__float_as_uint(hn) << 32) | (uint64_t)(uint32_t)it;
                __hip_atomic_store(&wb[(k << 2) + t], word,
                                   __ATOMIC_RELAXED, __HIP_MEMORY_SCOPE_AGENT);
            }
        }
    }
}

extern "C" void kernel_launch(void* const* d_in, const int* in_sizes, int n_in,
                              void* d_out, int out_size, void* d_ws, size_t ws_size,
                              hipStream_t stream)
{
    const float* x      = (const float*)d_in[0];
    const int*   ts     = (const int*)d_in[1];
    const float* proj_w = (const float*)d_in[2];
    const float* proj_b = (const float*)d_in[3];
    const float* te_w1  = (const float*)d_in[4];
    const float* te_b1  = (const float*)d_in[5];
    const float* te_w2  = (const float*)d_in[6];
    const float* te_b2  = (const float*)d_in[7];
    const float* Wih    = (const float*)d_in[8];
    const float* Whh    = (const float*)d_in[9];
    const float* bih    = (const float*)d_in[10];
    const float* bhh    = (const float*)d_in[11];
    const float* lin_w  = (const float*)d_in[12];
    const float* lin_b  = (const float*)d_in[13];
    float* out = (float*)d_out;

    char* ws = (char*)d_ws;
    const size_t MB16 = (size_t)NS * DT * 4;                    // 16 MiB
    float* bufA = (float*)ws;                                   // emb -> emb2 -> hall
    float* bufB = (float*)(ws + MB16);                          // h1 -> xp
    const size_t xg_f32_bytes  = (size_t)NS * 16384 * 4;        // 256 MiB
    const size_t xg_bf16_bytes = (size_t)NS * 16384 * 2;        // 128 MiB
    const bool use_f32_xg = ws_size >= 2 * MB16 + xg_f32_bytes + 16384 + 64;
    float*          XGf = (float*)(ws + 2 * MB16);
    __hip_bfloat16* XGb = (__hip_bfloat16*)(ws + 2 * MB16);
    uint64_t* hbuf = (uint64_t*)(ws + 2 * MB16 +
                                 (use_f32_xg ? xg_f32_bytes : xg_bf16_bytes));

    hipMemsetAsync(hbuf, 0, 2 * 1024 * sizeof(uint64_t), stream);

    // emb = sinusoidal(timesteps)
    emb_kernel<<<NS, 512, 0, stream>>>(ts, bufA);
    // h1 = silu(emb @ te_w1^T + te_b1)
    gemm_bt<true, false, 0><<<dim3(16, 32), 256, 0, stream>>>(
        bufA, te_w1, te_b1, nullptr, nullptr, bufB, nullptr, NS, DT, DT);
    // emb2 = h1 @ te_w2^T + te_b2
    gemm_bt<false, false, 0><<<dim3(16, 32), 256, 0, stream>>>(
        bufB, te_w2, te_b2, nullptr, nullptr, bufA, nullptr, NS, DT, DT);
    // xp = x @ proj_w^T + proj_b + emb2
    gemm_bt<false, true, 0><<<dim3(16, 32), 256, 0, stream>>>(
        x, proj_w, proj_b, nullptr, bufA, bufB, nullptr, NS, DT, DT);
    // XG[l] = xp @ Wih[l]^T + bih[l] + bhh[l]   (permuted layout), z = layer
    if (use_f32_xg) {
        gemm_bt<false, false, 2><<<dim3(64, 32, 4), 256, 0, stream>>>(
            bufB, Wih, bih, bhh, nullptr, XGf, nullptr, NS, H4, DT);
        seq_kernel<float><<<256, 256, 0, stream>>>(Whh, XGf, bufA, hbuf);
    } else {
        gemm_bt<false, false, 1><<<dim3(64, 32, 4), 256, 0, stream>>>(
            bufB, Wih, bih, bhh, nullptr, nullptr, XGb, NS, H4, DT);
        seq_kernel<__hip_bfloat16><<<256, 256, 0, stream>>>(Whh, XGb, bufA, hbuf);
    }
    // out = hall @ lin_w^T + lin_b
    gemm_bt<false, false, 0><<<dim3(16, 32), 256, 0, stream>>>(
        bufA, lin_w, lin_b, nullptr, nullptr, out, nullptr, NS, DT, DT);
}